// Round 1
// 2186.669 us; speedup vs baseline: 1.3251x; 1.3251x over previous
//
#include <hip/hip_runtime.h>

// ---------------- problem constants ----------------
constexpr int Bc   = 4;
constexpr int Cc   = 32;
constexpr int Hc   = 512;
constexpr int Wc   = 1024;
constexpr int HOc  = 512;
constexpr int WOc  = 1024;
constexpr int NPIX  = Hc * Wc;      // 524288 input pixels
constexpr int PLANE = HOc * WOc;    // output pixels per (b,c)
constexpr int BCn   = Bc * Cc;      // 128 channel planes

// ---------------- tiling ----------------
constexpr int TH = 32, TW = 32;                 // output tile (y,x)
constexpr int TILES_X = WOc / TW;               // 32
constexpr int TILES_Y = HOc / TH;               // 16
constexpr int NT = TILES_X * TILES_Y;           // 512 tiles
constexpr int G  = 8;                           // channels per block / slab
constexpr int CG = BCn / G;                     // 16 channel groups
constexpr int LDSW   = TW + 1;                  // 33 (apron col)
constexpr int TCELLS = (TH + 1) * (TW + 1);     // 1089 cells incl. apron

__device__ __forceinline__ int tile_of(float cx, float cy, int& x0, int& y0) {
    x0 = (int)floorf(cx);
    y0 = (int)floorf(cy);
    int tx = min(max(x0 >> 5, 0), TILES_X - 1);
    int ty = min(max(y0 >> 5, 0), TILES_Y - 1);
    return ty * TILES_X + tx;
}

// ---------------- K1a: per-tile histogram ----------------
__global__ __launch_bounds__(256) void hist_kernel(
    const float2* __restrict__ smap, int* __restrict__ count)
{
    __shared__ int h[NT];
    for (int i = threadIdx.x; i < NT; i += 256) h[i] = 0;
    __syncthreads();
    const int stride = gridDim.x * 256;
    for (int p = blockIdx.x * 256 + threadIdx.x; p < NPIX; p += stride) {
        float2 c = smap[p];
        int x0, y0;
        int t = tile_of(c.x, c.y, x0, y0);
        atomicAdd(&h[t], 1);
    }
    __syncthreads();
    for (int i = threadIdx.x; i < NT; i += 256)
        if (h[i]) atomicAdd(&count[i], h[i]);
}

// ---------------- K1b: exclusive scan over NT=512 bins ----------------
__global__ __launch_bounds__(512) void scan_kernel(
    const int* __restrict__ count, int* __restrict__ off)
{
    __shared__ int s[NT];
    int tid = threadIdx.x;
    s[tid] = count[tid];
    __syncthreads();
    for (int d = 1; d < NT; d <<= 1) {
        int v = (tid >= d) ? s[tid - d] : 0;
        __syncthreads();
        s[tid] += v;
        __syncthreads();
    }
    if (tid == 0) off[0] = 0;
    off[tid + 1] = s[tid];
}

// ---------------- K1c: compute sorted slot pos[p]; emit sorted smap ----------------
__global__ __launch_bounds__(256) void scatter_pos_kernel(
    const float2* __restrict__ smap, const int* __restrict__ off,
    int* __restrict__ cursor, int* __restrict__ pos,
    float2* __restrict__ smap_g)
{
    __shared__ int h[NT];
    __shared__ int base[NT];
    const int tid = threadIdx.x;
    for (int i = tid; i < NT; i += 256) h[i] = 0;
    __syncthreads();
    const int p = blockIdx.x * 256 + tid;             // grid is exactly NPIX/256
    const float2 c = smap[p];
    int x0, y0;
    const int t = tile_of(c.x, c.y, x0, y0);
    atomicAdd(&h[t], 1);
    __syncthreads();
    for (int i = tid; i < NT; i += 256) {
        int cnt = h[i];
        base[i] = cnt ? atomicAdd(&cursor[i], cnt) : 0;
        h[i] = 0;
    }
    __syncthreads();
    const int r = atomicAdd(&h[t], 1);
    const int posi = off[t] + base[t] + r;
    pos[p] = posi;
    smap_g[posi] = c;                                  // sorted copy of the map
}

// ---------------- K1d: transpose x into CSR order ----------------
// Reads x coalesced (input-pixel order, float4 streams), writes each pixel's
// 8-channel chunk as one contiguous 32B block at its sorted slot.
__global__ __launch_bounds__(256) void gather_kernel(
    const float* __restrict__ x, const int* __restrict__ pos,
    float* __restrict__ xg, int cg0, int ncg)
{
    const int p = (blockIdx.x * 256 + threadIdx.x) * 4;   // 4 pixels/thread
    const int4 d = *reinterpret_cast<const int4*>(pos + p);
    for (int g = 0; g < ncg; ++g) {
        const float* xp = x + (long)(cg0 + g) * G * NPIX + p;
        float4 r[8];
#pragma unroll
        for (int k = 0; k < 8; ++k)
            r[k] = *reinterpret_cast<const float4*>(xp + (long)k * NPIX);
        float* o0 = xg + ((long)g * NPIX + d.x) * 8;
        float* o1 = xg + ((long)g * NPIX + d.y) * 8;
        float* o2 = xg + ((long)g * NPIX + d.z) * 8;
        float* o3 = xg + ((long)g * NPIX + d.w) * 8;
        *reinterpret_cast<float4*>(o0)     = make_float4(r[0].x, r[1].x, r[2].x, r[3].x);
        *reinterpret_cast<float4*>(o0 + 4) = make_float4(r[4].x, r[5].x, r[6].x, r[7].x);
        *reinterpret_cast<float4*>(o1)     = make_float4(r[0].y, r[1].y, r[2].y, r[3].y);
        *reinterpret_cast<float4*>(o1 + 4) = make_float4(r[4].y, r[5].y, r[6].y, r[7].y);
        *reinterpret_cast<float4*>(o2)     = make_float4(r[0].z, r[1].z, r[2].z, r[3].z);
        *reinterpret_cast<float4*>(o2 + 4) = make_float4(r[4].z, r[5].z, r[6].z, r[7].z);
        *reinterpret_cast<float4*>(o3)     = make_float4(r[0].w, r[1].w, r[2].w, r[3].w);
        *reinterpret_cast<float4*>(o3 + 4) = make_float4(r[4].w, r[5].w, r[6].w, r[7].w);
    }
}

// ---------------- K2: per-(tile, channel-group) LDS accumulation ----------------
// All global reads are now sequential streams: xg slab segment + sorted smap.
__global__ __launch_bounds__(256) void accum_kernel(
    const float*  __restrict__ xg,
    const float2* __restrict__ smap_g,
    const int*    __restrict__ off,
    float*        __restrict__ out,
    int cg0)
{
    __shared__ float acc[G][TCELLS];
    const int t     = blockIdx.x;
    const int gslab = blockIdx.y;
    const int bc0   = (cg0 + gslab) * G;
    const int tx0 = (t % TILES_X) * TW;
    const int ty0 = (t / TILES_X) * TH;
    const int tid = threadIdx.x;

    for (int i = tid; i < G * TCELLS; i += 256)
        (&acc[0][0])[i] = 0.0f;
    __syncthreads();

    const int lo = off[t], n = off[t + 1] - lo;
    const float* xs = xg + (long)gslab * NPIX * 8;
    for (int i = tid; i < n; i += 256) {
        const float2 c = smap_g[lo + i];
        const float x0f = floorf(c.x);
        const float y0f = floorf(c.y);
        const float wx = c.x - x0f;
        const float wy = c.y - y0f;
        const int lx = (int)x0f - tx0;
        const int ly = (int)y0f - ty0;
        if ((unsigned)lx >= (unsigned)TW || (unsigned)ly >= (unsigned)TH) continue; // safety
        const float w00 = (1.0f - wx) * (1.0f - wy);
        const float w10 = wx * (1.0f - wy);
        const float w01 = (1.0f - wx) * wy;
        const float w11 = wx * wy;
        const int a = ly * LDSW + lx;
        const float4 va = *reinterpret_cast<const float4*>(xs + (long)(lo + i) * 8);
        const float4 vb = *reinterpret_cast<const float4*>(xs + (long)(lo + i) * 8 + 4);
        const float v[8] = {va.x, va.y, va.z, va.w, vb.x, vb.y, vb.z, vb.w};
#pragma unroll
        for (int k = 0; k < G; ++k) {
            atomicAdd(&acc[k][a],            v[k] * w00);
            atomicAdd(&acc[k][a + 1],        v[k] * w10);
            atomicAdd(&acc[k][a + LDSW],     v[k] * w01);
            atomicAdd(&acc[k][a + LDSW + 1], v[k] * w11);
        }
    }
    __syncthreads();

    // Write out: interior cells owned exclusively by this tile -> plain store.
    // First row/col and apron row/col -> global atomic add.
    for (int idx = tid; idx < TCELLS; idx += 256) {
        const int r = idx / LDSW;
        const int cc = idx - r * LDSW;
        const int gy = ty0 + r, gx = tx0 + cc;
        if (gy >= HOc || gx >= WOc) continue;
        const bool edge = (r == 0) | (cc == 0) | (r == TH) | (cc == TW);
        const long o = (long)gy * WOc + gx;
#pragma unroll
        for (int k = 0; k < G; ++k) {
            const float v = acc[k][idx];
            float* op = out + (long)(bc0 + k) * PLANE + o;
            if (edge) { if (v != 0.0f) unsafeAtomicAdd(op, v); }
            else      { *op = v; }
        }
    }
}

// ---------------- fallback: direct global-atomic splat ----------------
__global__ __launch_bounds__(256) void splat_kernel(
    const float* __restrict__ x, const float2* __restrict__ smap,
    float* __restrict__ out)
{
    const int p = blockIdx.x * blockDim.x + threadIdx.x;
    if (p >= NPIX) return;
    const float2 c = smap[p];
    const float x0f = floorf(c.x), y0f = floorf(c.y);
    const float wx = c.x - x0f, wy = c.y - y0f;
    const int x0 = (int)x0f, y0 = (int)y0f;
    const float w00 = (1.0f-wx)*(1.0f-wy), w10 = wx*(1.0f-wy);
    const float w01 = (1.0f-wx)*wy, w11 = wx*wy;
    const bool vx0 = (x0>=0)&(x0<WOc), vx1 = (x0+1>=0)&(x0+1<WOc);
    const bool vy0 = (y0>=0)&(y0<HOc), vy1 = (y0+1>=0)&(y0+1<HOc);
    const long base = (long)y0*WOc + x0;
    const int bc0 = blockIdx.y * 4;
#pragma unroll
    for (int k = 0; k < 4; ++k) {
        const int bc = bc0 + k;
        const float v = x[(long)bc*NPIX + p];
        float* o = out + (long)bc*PLANE;
        if (vx0 & vy0) unsafeAtomicAdd(o + base,          v*w00);
        if (vx1 & vy0) unsafeAtomicAdd(o + base + 1,      v*w10);
        if (vx0 & vy1) unsafeAtomicAdd(o + base + WOc,    v*w01);
        if (vx1 & vy1) unsafeAtomicAdd(o + base + WOc+1,  v*w11);
    }
}

extern "C" void kernel_launch(void* const* d_in, const int* in_sizes, int n_in,
                              void* d_out, int out_size, void* d_ws, size_t ws_size,
                              hipStream_t stream) {
    const float*  x    = (const float*)d_in[0];
    const float2* smap = (const float2*)d_in[1];
    float*        out  = (float*)d_out;

    hipMemsetAsync(d_out, 0, (size_t)out_size * sizeof(float), stream);

    // ---- workspace layout ----
    // [pos NPIX int][count NT][cursor NT][off NT+1] | pad | [smap_g NPIX float2] | pad | [xg slabs]
    const size_t int_bytes  = sizeof(int) * ((size_t)NPIX + 3 * NT + 1);
    size_t ofs = (int_bytes + 255) & ~(size_t)255;
    const size_t smapg_ofs = ofs;
    ofs += sizeof(float2) * (size_t)NPIX;
    ofs = (ofs + 255) & ~(size_t)255;
    const size_t xg_ofs = ofs;
    const size_t slab_bytes = (size_t)NPIX * G * sizeof(float);   // 16 MiB per 8-ch slab

    long slabs = 0;
    if (ws_size > xg_ofs) slabs = (long)((ws_size - xg_ofs) / slab_bytes);
    if (slabs > CG) slabs = CG;

    if (slabs < 1) {
        // workspace too small: direct-atomic fallback (correct, slow)
        dim3 grid(NPIX / 256, BCn / 4);
        splat_kernel<<<grid, 256, 0, stream>>>(x, smap, out);
        return;
    }

    char* wsb      = (char*)d_ws;
    int*  pos      = (int*)wsb;
    int*  count    = pos + NPIX;
    int*  cursor   = count + NT;
    int*  off      = cursor + NT;                    // NT+1
    float2* smap_g = (float2*)(wsb + smapg_ofs);
    float*  xg     = (float*)(wsb + xg_ofs);

    hipMemsetAsync(count, 0, sizeof(int) * 2 * NT, stream);      // count + cursor

    hist_kernel       <<<256, 256, 0, stream>>>(smap, count);
    scan_kernel       <<<1, 512, 0, stream>>>(count, off);
    scatter_pos_kernel<<<NPIX / 256, 256, 0, stream>>>(smap, off, cursor, pos, smap_g);

    for (int cg0 = 0; cg0 < CG; cg0 += (int)slabs) {
        int ncg = CG - cg0;
        if (ncg > slabs) ncg = (int)slabs;
        gather_kernel<<<NPIX / 1024, 256, 0, stream>>>(x, pos, xg, cg0, ncg);
        dim3 grid2(NT, ncg);
        accum_kernel <<<grid2, 256, 0, stream>>>(xg, smap_g, off, out, cg0);
    }
}

// Round 2
// 1981.302 us; speedup vs baseline: 1.4625x; 1.1037x over previous
//
#include <hip/hip_runtime.h>

// ---------------- problem constants ----------------
constexpr int Bc   = 4;
constexpr int Cc   = 32;
constexpr int Hc   = 512;
constexpr int Wc   = 1024;
constexpr int HOc  = 512;
constexpr int WOc  = 1024;
constexpr int NPIX  = Hc * Wc;      // 524288 input pixels
constexpr int PLANE = HOc * WOc;    // output pixels per (b,c)
constexpr int BCn   = Bc * Cc;      // 128 channel planes

// ---------------- tiling ----------------
constexpr int TH = 32, TW = 32;                 // output tile (y,x)
constexpr int TILES_X = WOc / TW;               // 32
constexpr int TILES_Y = HOc / TH;               // 16
constexpr int NT = TILES_X * TILES_Y;           // 512 tiles
constexpr int G  = 8;                           // channels per slab
constexpr int CG = BCn / G;                     // 16 channel groups
constexpr int LDSW   = TW + 1;                  // 33 (apron col)
constexpr int TCELLS = (TH + 1) * (TW + 1);     // 1089 cells incl. apron
constexpr int NBIN   = TCELLS + 1;              // + out-of-bounds bucket
constexpr int NMAX   = 1280;                    // max pixels/tile on fast path
constexpr int EMAX   = 4 * NMAX;                // max staged entries

__device__ __forceinline__ int tile_of(float cx, float cy, int& x0, int& y0) {
    x0 = (int)floorf(cx);
    y0 = (int)floorf(cy);
    int tx = min(max(x0 >> 5, 0), TILES_X - 1);
    int ty = min(max(y0 >> 5, 0), TILES_Y - 1);
    return ty * TILES_X + tx;
}

// ---------------- K1a: per-tile histogram ----------------
__global__ __launch_bounds__(256) void hist_kernel(
    const float2* __restrict__ smap, int* __restrict__ count)
{
    __shared__ int h[NT];
    for (int i = threadIdx.x; i < NT; i += 256) h[i] = 0;
    __syncthreads();
    const int stride = gridDim.x * 256;
    for (int p = blockIdx.x * 256 + threadIdx.x; p < NPIX; p += stride) {
        float2 c = smap[p];
        int x0, y0;
        int t = tile_of(c.x, c.y, x0, y0);
        atomicAdd(&h[t], 1);
    }
    __syncthreads();
    for (int i = threadIdx.x; i < NT; i += 256)
        if (h[i]) atomicAdd(&count[i], h[i]);
}

// ---------------- K1b: exclusive scan over NT=512 bins ----------------
__global__ __launch_bounds__(512) void scan_kernel(
    const int* __restrict__ count, int* __restrict__ off)
{
    __shared__ int s[NT];
    int tid = threadIdx.x;
    s[tid] = count[tid];
    __syncthreads();
    for (int d = 1; d < NT; d <<= 1) {
        int v = (tid >= d) ? s[tid - d] : 0;
        __syncthreads();
        s[tid] += v;
        __syncthreads();
    }
    if (tid == 0) off[0] = 0;
    off[tid + 1] = s[tid];
}

// ---------------- K1c: sorted slot pos[p]; emit sorted smap ----------------
__global__ __launch_bounds__(256) void scatter_pos_kernel(
    const float2* __restrict__ smap, const int* __restrict__ off,
    int* __restrict__ cursor, int* __restrict__ pos,
    float2* __restrict__ smap_g)
{
    __shared__ int h[NT];
    __shared__ int base[NT];
    const int tid = threadIdx.x;
    for (int i = tid; i < NT; i += 256) h[i] = 0;
    __syncthreads();
    const int p = blockIdx.x * 256 + tid;             // grid is exactly NPIX/256
    const float2 c = smap[p];
    int x0, y0;
    const int t = tile_of(c.x, c.y, x0, y0);
    atomicAdd(&h[t], 1);
    __syncthreads();
    for (int i = tid; i < NT; i += 256) {
        int cnt = h[i];
        base[i] = cnt ? atomicAdd(&cursor[i], cnt) : 0;
        h[i] = 0;
    }
    __syncthreads();
    const int r = atomicAdd(&h[t], 1);
    const int posi = off[t] + base[t] + r;
    pos[p] = posi;
    smap_g[posi] = c;
}

// ---------------- K1d: per-tile cell-level CSR (built ONCE, all channels) ---
// For each tile: histogram 4 corner-contributions per pixel over the 1089
// cells (+1 oob bucket), exclusive scan, then scatter (pixel-idx, weight)
// entries. These are the only LDS atomics left, 8 lane-ops/pixel total.
__global__ __launch_bounds__(256) void cellbuild_kernel(
    const float2* __restrict__ smap_g, const int* __restrict__ off,
    ushort* __restrict__ ent, float* __restrict__ entw,
    int* __restrict__ gcello)
{
    __shared__ unsigned cnt[NBIN];
    __shared__ unsigned coff[NBIN + 1];
    __shared__ unsigned psum[256];
    const int t   = blockIdx.x;
    const int tx0 = (t % TILES_X) * TW;
    const int ty0 = (t / TILES_X) * TH;
    const int lo  = off[t];
    const int n   = off[t + 1] - lo;
    const int nn  = min(n, NMAX);
    const int tid = threadIdx.x;

    for (int i = tid; i < NBIN; i += 256) cnt[i] = 0;
    __syncthreads();

    for (int i = tid; i < nn; i += 256) {
        float2 c = smap_g[lo + i];
        int x0 = (int)floorf(c.x), y0 = (int)floorf(c.y);
        int lx = x0 - tx0, ly = y0 - ty0;
        if ((unsigned)lx < (unsigned)TW && (unsigned)ly < (unsigned)TH) {
            int a = ly * LDSW + lx;
            atomicAdd(&cnt[a], 1u);
            atomicAdd(&cnt[a + 1], 1u);
            atomicAdd(&cnt[a + LDSW], 1u);
            atomicAdd(&cnt[a + LDSW + 1], 1u);
        } else {
            atomicAdd(&cnt[TCELLS], 1u);   // oob bucket
        }
    }
    __syncthreads();

    // exclusive scan over NBIN bins (blocked: 5 bins/thread + block scan)
    constexpr int BPT = (NBIN + 255) / 256;   // 5
    unsigned loc[BPT];
    unsigned s = 0;
    for (int j = 0; j < BPT; ++j) {
        int b = tid * BPT + j;
        unsigned v = (b < NBIN) ? cnt[b] : 0u;
        loc[j] = s; s += v;
    }
    psum[tid] = s;
    __syncthreads();
    for (int d = 1; d < 256; d <<= 1) {
        unsigned v = (tid >= d) ? psum[tid - d] : 0u;
        __syncthreads();
        psum[tid] += v;
        __syncthreads();
    }
    unsigned base = (tid > 0) ? psum[tid - 1] : 0u;
    for (int j = 0; j < BPT; ++j) {
        int b = tid * BPT + j;
        if (b < NBIN) coff[b] = base + loc[j];
    }
    if (tid == 255) coff[NBIN] = psum[255];
    __syncthreads();

    // cursor = coff; publish offsets
    for (int i = tid; i < NBIN; i += 256) cnt[i] = coff[i];
    for (int i = tid; i < NBIN + 1; i += 256)
        gcello[t * (NBIN + 1) + i] = (int)coff[i];
    __syncthreads();

    // scatter entries
    const int ebase = 4 * lo;
    for (int i = tid; i < nn; i += 256) {
        float2 c = smap_g[lo + i];
        float fx = floorf(c.x), fy = floorf(c.y);
        float wx = c.x - fx, wy = c.y - fy;
        int lx = (int)fx - tx0, ly = (int)fy - ty0;
        if ((unsigned)lx < (unsigned)TW && (unsigned)ly < (unsigned)TH) {
            int a = ly * LDSW + lx;
            float w00 = (1.f - wx) * (1.f - wy), w10 = wx * (1.f - wy);
            float w01 = (1.f - wx) * wy,         w11 = wx * wy;
            unsigned e;
            e = atomicAdd(&cnt[a], 1u);            ent[ebase + e] = (ushort)i; entw[ebase + e] = w00;
            e = atomicAdd(&cnt[a + 1], 1u);        ent[ebase + e] = (ushort)i; entw[ebase + e] = w10;
            e = atomicAdd(&cnt[a + LDSW], 1u);     ent[ebase + e] = (ushort)i; entw[ebase + e] = w01;
            e = atomicAdd(&cnt[a + LDSW + 1], 1u); ent[ebase + e] = (ushort)i; entw[ebase + e] = w11;
        } else {
            unsigned e = atomicAdd(&cnt[TCELLS], 1u);
            ent[ebase + e] = (ushort)i; entw[ebase + e] = 0.f;
        }
    }
}

// ---------------- K1e: transpose x into CSR order ----------------
__global__ __launch_bounds__(256) void gather_kernel(
    const float* __restrict__ x, const int* __restrict__ pos,
    float* __restrict__ xg, int cg0, int ncg)
{
    const int p = (blockIdx.x * 256 + threadIdx.x) * 4;   // 4 pixels/thread
    const int4 d = *reinterpret_cast<const int4*>(pos + p);
    for (int g = 0; g < ncg; ++g) {
        const float* xp = x + (long)(cg0 + g) * G * NPIX + p;
        float4 r[8];
#pragma unroll
        for (int k = 0; k < 8; ++k)
            r[k] = *reinterpret_cast<const float4*>(xp + (long)k * NPIX);
        float* o0 = xg + ((long)g * NPIX + d.x) * 8;
        float* o1 = xg + ((long)g * NPIX + d.y) * 8;
        float* o2 = xg + ((long)g * NPIX + d.z) * 8;
        float* o3 = xg + ((long)g * NPIX + d.w) * 8;
        *reinterpret_cast<float4*>(o0)     = make_float4(r[0].x, r[1].x, r[2].x, r[3].x);
        *reinterpret_cast<float4*>(o0 + 4) = make_float4(r[4].x, r[5].x, r[6].x, r[7].x);
        *reinterpret_cast<float4*>(o1)     = make_float4(r[0].y, r[1].y, r[2].y, r[3].y);
        *reinterpret_cast<float4*>(o1 + 4) = make_float4(r[4].y, r[5].y, r[6].y, r[7].y);
        *reinterpret_cast<float4*>(o2)     = make_float4(r[0].z, r[1].z, r[2].z, r[3].z);
        *reinterpret_cast<float4*>(o2 + 4) = make_float4(r[4].z, r[5].z, r[6].z, r[7].z);
        *reinterpret_cast<float4*>(o3)     = make_float4(r[0].w, r[1].w, r[2].w, r[3].w);
        *reinterpret_cast<float4*>(o3 + 4) = make_float4(r[4].w, r[5].w, r[6].w, r[7].w);
    }
}

// ---------------- K2: per-(tile, slab) gather-accumulate, NO atomics -------
__global__ __launch_bounds__(512) void accum_kernel(
    const float*  __restrict__ xg,
    const float2* __restrict__ smap_g,
    const int*    __restrict__ off,
    const ushort* __restrict__ ent,
    const float*  __restrict__ entw,
    const int*    __restrict__ gcello,
    float*        __restrict__ out, int cg0)
{
    __shared__ float4   vals4[2 * NMAX];     // 40 KB: 8ch values per pixel
    __shared__ float    wl[EMAX];            // 20.5 KB: entry weights
    __shared__ unsigned entl[EMAX / 2];      // 10.25 KB: entry pixel-idx (u16 pairs)
    __shared__ unsigned offl[NBIN + 1];      // 4.3 KB: cell offsets
    const int t     = blockIdx.x;
    const int gslab = blockIdx.y;
    const int bc0   = (cg0 + gslab) * G;
    const int tx0 = (t % TILES_X) * TW;
    const int ty0 = (t / TILES_X) * TH;
    const int tid = threadIdx.x;
    const int lo = off[t], n = off[t + 1] - lo, nn = min(n, NMAX);
    const float* xs = xg + (long)gslab * NPIX * 8;

    // ---- stage (all coalesced streams) ----
    const float4* vsrc = (const float4*)(xs + (long)lo * 8);
    for (int j = tid; j < nn * 2; j += 512) vals4[j] = vsrc[j];
    const unsigned* esrc = (const unsigned*)(ent + 4 * lo);   // 4*lo u16 = 4-byte aligned
    for (int j = tid; j < nn * 2; j += 512) entl[j] = esrc[j];
    const float* wsrc = entw + 4 * lo;
    for (int j = tid; j < nn * 4; j += 512) wl[j] = wsrc[j];
    for (int j = tid; j < NBIN + 1; j += 512) offl[j] = (unsigned)gcello[t * (NBIN + 1) + j];
    __syncthreads();

    const ushort* entl16 = (const ushort*)entl;

    // ---- per-cell register accumulation + direct writeout ----
    for (int c = tid; c < TCELLS; c += 512) {
        const unsigned e0 = offl[c], e1 = offl[c + 1];
        float a0 = 0, a1 = 0, a2 = 0, a3 = 0, a4 = 0, a5 = 0, a6 = 0, a7 = 0;
        for (unsigned e = e0; e < e1; ++e) {
            const int idx = entl16[e];
            const float w = wl[e];
            const float4 va = vals4[idx * 2];
            const float4 vb = vals4[idx * 2 + 1];
            a0 += va.x * w; a1 += va.y * w; a2 += va.z * w; a3 += va.w * w;
            a4 += vb.x * w; a5 += vb.y * w; a6 += vb.z * w; a7 += vb.w * w;
        }
        const int r = c / LDSW, cc = c - r * LDSW;
        const int gy = ty0 + r, gx = tx0 + cc;
        if (gy >= HOc || gx >= WOc) continue;
        const bool edge = (r == 0) | (cc == 0) | (r == TH) | (cc == TW);
        const long o = (long)gy * WOc + gx;
        const float av[8] = {a0, a1, a2, a3, a4, a5, a6, a7};
#pragma unroll
        for (int k = 0; k < 8; ++k) {
            float* op = out + (long)(bc0 + k) * PLANE + o;
            if (edge) { if (av[k] != 0.0f) unsafeAtomicAdd(op, av[k]); }
            else      { *op = av[k]; }
        }
    }
    __syncthreads();   // interior stores complete before any same-block atomics below

    // ---- oob bucket (pixels whose tile was clamped): bounds-checked atomics.
    {
        const unsigned e0 = offl[TCELLS], e1 = offl[NBIN];
        for (unsigned e = e0 + tid; e < e1; e += 512) {
            const int idx = entl16[e];
            const float2 c2 = smap_g[lo + idx];
            const float fx = floorf(c2.x), fy = floorf(c2.y);
            const float wx = c2.x - fx, wy = c2.y - fy;
            const int x0 = (int)fx, y0 = (int)fy;
            const float4 va = vals4[idx * 2], vb = vals4[idx * 2 + 1];
            const float v[8] = {va.x, va.y, va.z, va.w, vb.x, vb.y, vb.z, vb.w};
            const float cw[4] = {(1.f - wx) * (1.f - wy), wx * (1.f - wy),
                                 (1.f - wx) * wy,         wx * wy};
            const int cxs[4] = {x0, x0 + 1, x0, x0 + 1};
            const int cys[4] = {y0, y0, y0 + 1, y0 + 1};
#pragma unroll
            for (int q = 0; q < 4; ++q) {
                if (cxs[q] < 0 || cxs[q] >= WOc || cys[q] < 0 || cys[q] >= HOc) continue;
                const long o = (long)cys[q] * WOc + cxs[q];
#pragma unroll
                for (int k = 0; k < 8; ++k)
                    unsafeAtomicAdd(out + (long)(bc0 + k) * PLANE + o, v[k] * cw[q]);
            }
        }
    }

    // ---- overflow pixels (i >= NMAX): direct atomics (never taken here) ----
    for (int i = NMAX + tid; i < n; i += 512) {
        const float2 c2 = smap_g[lo + i];
        const float fx = floorf(c2.x), fy = floorf(c2.y);
        const float wx = c2.x - fx, wy = c2.y - fy;
        const int x0 = (int)fx, y0 = (int)fy;
        const float4 va = *((const float4*)(xs + (long)(lo + i) * 8));
        const float4 vb = *((const float4*)(xs + (long)(lo + i) * 8) + 1);
        const float v[8] = {va.x, va.y, va.z, va.w, vb.x, vb.y, vb.z, vb.w};
        const float cw[4] = {(1.f - wx) * (1.f - wy), wx * (1.f - wy),
                             (1.f - wx) * wy,         wx * wy};
        const int cxs[4] = {x0, x0 + 1, x0, x0 + 1};
        const int cys[4] = {y0, y0, y0 + 1, y0 + 1};
#pragma unroll
        for (int q = 0; q < 4; ++q) {
            if (cxs[q] < 0 || cxs[q] >= WOc || cys[q] < 0 || cys[q] >= HOc) continue;
            const long o = (long)cys[q] * WOc + cxs[q];
#pragma unroll
            for (int k = 0; k < 8; ++k)
                unsafeAtomicAdd(out + (long)(bc0 + k) * PLANE + o, v[k] * cw[q]);
        }
    }
}

// ---------------- fallback: direct global-atomic splat ----------------
__global__ __launch_bounds__(256) void splat_kernel(
    const float* __restrict__ x, const float2* __restrict__ smap,
    float* __restrict__ out)
{
    const int p = blockIdx.x * blockDim.x + threadIdx.x;
    if (p >= NPIX) return;
    const float2 c = smap[p];
    const float x0f = floorf(c.x), y0f = floorf(c.y);
    const float wx = c.x - x0f, wy = c.y - y0f;
    const int x0 = (int)x0f, y0 = (int)y0f;
    const float w00 = (1.0f-wx)*(1.0f-wy), w10 = wx*(1.0f-wy);
    const float w01 = (1.0f-wx)*wy, w11 = wx*wy;
    const bool vx0 = (x0>=0)&(x0<WOc), vx1 = (x0+1>=0)&(x0+1<WOc);
    const bool vy0 = (y0>=0)&(y0<HOc), vy1 = (y0+1>=0)&(y0+1<HOc);
    const long base = (long)y0*WOc + x0;
    const int bc0 = blockIdx.y * 4;
#pragma unroll
    for (int k = 0; k < 4; ++k) {
        const int bc = bc0 + k;
        const float v = x[(long)bc*NPIX + p];
        float* o = out + (long)bc*PLANE;
        if (vx0 & vy0) unsafeAtomicAdd(o + base,          v*w00);
        if (vx1 & vy0) unsafeAtomicAdd(o + base + 1,      v*w10);
        if (vx0 & vy1) unsafeAtomicAdd(o + base + WOc,    v*w01);
        if (vx1 & vy1) unsafeAtomicAdd(o + base + WOc+1,  v*w11);
    }
}

extern "C" void kernel_launch(void* const* d_in, const int* in_sizes, int n_in,
                              void* d_out, int out_size, void* d_ws, size_t ws_size,
                              hipStream_t stream) {
    const float*  x    = (const float*)d_in[0];
    const float2* smap = (const float2*)d_in[1];
    float*        out  = (float*)d_out;

    hipMemsetAsync(d_out, 0, (size_t)out_size * sizeof(float), stream);

    // ---- workspace layout ----
    // [pos NPIX][count NT][cursor NT][off NT+1][gcello NT*(NBIN+1)]
    //   | smap_g NPIX float2 | ent 4*NPIX u16 | entw 4*NPIX f32 | xg slabs
    const size_t ints = (size_t)NPIX + 3 * NT + 1 + (size_t)NT * (NBIN + 1);
    size_t ofs = (ints * sizeof(int) + 255) & ~(size_t)255;
    const size_t smapg_ofs = ofs;
    ofs += sizeof(float2) * (size_t)NPIX;
    ofs = (ofs + 255) & ~(size_t)255;
    const size_t ent_ofs = ofs;
    ofs += sizeof(ushort) * 4 * (size_t)NPIX;
    ofs = (ofs + 255) & ~(size_t)255;
    const size_t entw_ofs = ofs;
    ofs += sizeof(float) * 4 * (size_t)NPIX;
    ofs = (ofs + 255) & ~(size_t)255;
    const size_t xg_ofs = ofs;
    const size_t slab_bytes = (size_t)NPIX * G * sizeof(float);   // 16 MiB

    long slabs = 0;
    if (ws_size > xg_ofs) slabs = (long)((ws_size - xg_ofs) / slab_bytes);
    if (slabs > CG) slabs = CG;

    if (slabs < 1) {
        dim3 grid(NPIX / 256, BCn / 4);
        splat_kernel<<<grid, 256, 0, stream>>>(x, smap, out);
        return;
    }

    char* wsb      = (char*)d_ws;
    int*  pos      = (int*)wsb;
    int*  count    = pos + NPIX;
    int*  cursor   = count + NT;
    int*  off      = cursor + NT;                    // NT+1
    int*  gcello   = off + NT + 1;                   // NT*(NBIN+1)
    float2* smap_g = (float2*)(wsb + smapg_ofs);
    ushort* ent    = (ushort*)(wsb + ent_ofs);
    float*  entw   = (float*)(wsb + entw_ofs);
    float*  xg     = (float*)(wsb + xg_ofs);

    hipMemsetAsync(count, 0, sizeof(int) * 2 * NT, stream);      // count + cursor

    hist_kernel       <<<256, 256, 0, stream>>>(smap, count);
    scan_kernel       <<<1, 512, 0, stream>>>(count, off);
    scatter_pos_kernel<<<NPIX / 256, 256, 0, stream>>>(smap, off, cursor, pos, smap_g);
    cellbuild_kernel  <<<NT, 256, 0, stream>>>(smap_g, off, ent, entw, gcello);

    for (int cg0 = 0; cg0 < CG; cg0 += (int)slabs) {
        int ncg = CG - cg0;
        if (ncg > slabs) ncg = (int)slabs;
        gather_kernel<<<NPIX / 1024, 256, 0, stream>>>(x, pos, xg, cg0, ncg);
        dim3 grid2(NT, ncg);
        accum_kernel <<<grid2, 512, 0, stream>>>(xg, smap_g, off, ent, entw, gcello, out, cg0);
    }
}